// Round 1
// baseline (504.597 us; speedup 1.0000x reference)
//
#include <hip/hip_runtime.h>
#include <hip/hip_bf16.h>
#include <stdint.h>

// LNSLinear inference: out[m,n] = sign(S[m,n]) * P[m,n] + bias[n]
//   P = (|x|) @ (|w|)^T   (eps=1e-8 negligible at bf16 precision)
//   S = sign(x) @ sign(w)^T  (exact in bf16 MFMA: +-1 inputs, fp32 int accumulate)
// M = 262144, N = 256, K = 256 (all divisible by tile dims; no bounds checks)

#define K_DIM 256
#define N_DIM 256
#define BM 128
#define BN 128
#define BK 32
#define LDK 40  // padded LDS row stride (elems); 80 B = 5*16 B -> 16B-aligned frags, 2-way banks

typedef float f32x4 __attribute__((ext_vector_type(4)));
typedef __bf16 bf16x4 __attribute__((ext_vector_type(4)));
typedef __bf16 bf16x8 __attribute__((ext_vector_type(8)));
typedef unsigned short u16x4v __attribute__((ext_vector_type(4)));
typedef unsigned short u16x8v __attribute__((ext_vector_type(8)));

__device__ __forceinline__ void store_abs_sgn(float4 v, unsigned short* pa, unsigned short* ps) {
    // abs -> bf16 RNE (native fptrunc), sign -> bf16 +-1.0 via bit trick
    bf16x4 h;
    h[0] = (__bf16)__builtin_fabsf(v.x);
    h[1] = (__bf16)__builtin_fabsf(v.y);
    h[2] = (__bf16)__builtin_fabsf(v.z);
    h[3] = (__bf16)__builtin_fabsf(v.w);
    unsigned int u0 = __float_as_uint(v.x), u1 = __float_as_uint(v.y);
    unsigned int u2 = __float_as_uint(v.z), u3 = __float_as_uint(v.w);
    u16x4v s;
    s[0] = (unsigned short)(0x3F80u | ((u0 >> 16) & 0x8000u));
    s[1] = (unsigned short)(0x3F80u | ((u1 >> 16) & 0x8000u));
    s[2] = (unsigned short)(0x3F80u | ((u2 >> 16) & 0x8000u));
    s[3] = (unsigned short)(0x3F80u | ((u3 >> 16) & 0x8000u));
    *(u16x4v*)pa = __builtin_bit_cast(u16x4v, h);
    *(u16x4v*)ps = s;
}

__global__ __launch_bounds__(256, 2)
void lns_gemm_kernel(const float* __restrict__ X, const float* __restrict__ W,
                     const float* __restrict__ bias, float* __restrict__ out, int M) {
    __shared__ unsigned short sAabs[BM * LDK];
    __shared__ unsigned short sAsgn[BM * LDK];
    __shared__ unsigned short sBabs[BN * LDK];
    __shared__ unsigned short sBsgn[BN * LDK];

    const int tid  = threadIdx.x;
    const int lane = tid & 63;
    const int wave = tid >> 6;
    const int quad = lane >> 4;
    const int l16  = lane & 15;
    const int mb   = blockIdx.y;
    const int nb   = blockIdx.x;
    const int wm   = (wave >> 1) * 64;  // wave's row offset inside the 128x128 tile
    const int wn   = (wave & 1) * 64;   // wave's col offset

    const float* Ax = X + (size_t)(mb * BM) * K_DIM;
    const float* Bw = W + (size_t)(nb * BN) * K_DIM;

    f32x4 accP[4][4];
    f32x4 accS[4][4];
#pragma unroll
    for (int i = 0; i < 4; ++i)
#pragma unroll
        for (int j = 0; j < 4; ++j) {
            accP[i][j] = (f32x4)(0.0f);
            accS[i][j] = (f32x4)(0.0f);
        }

    for (int k0 = 0; k0 < K_DIM; k0 += BK) {
        __syncthreads();  // previous iteration's frag reads complete before overwrite
        // Stage A (x) and B (w) tiles: 128 rows x 32 k each, fp32 -> bf16 abs/sign in LDS.
        // 1024 float4 per tile; 256 threads x 4 reps; thread covers k-contiguous float4.
#pragma unroll
        for (int i = 0; i < 4; ++i) {
            int f   = i * 256 + tid;
            int row = f >> 3;
            int kc  = (f & 7) << 2;
            float4 va = *(const float4*)(Ax + (size_t)row * K_DIM + k0 + kc);
            store_abs_sgn(va, &sAabs[row * LDK + kc], &sAsgn[row * LDK + kc]);
            float4 vb = *(const float4*)(Bw + (size_t)row * K_DIM + k0 + kc);
            store_abs_sgn(vb, &sBabs[row * LDK + kc], &sBsgn[row * LDK + kc]);
        }
        __syncthreads();

        // Fragment loads: A[m = l16][k = quad*8 + j], B[n = l16][k = quad*8 + j]
        bf16x8 aab[4], asg[4], bab[4], bsg[4];
#pragma unroll
        for (int mi = 0; mi < 4; ++mi) {
            int off = (wm + mi * 16 + l16) * LDK + quad * 8;
            aab[mi] = __builtin_bit_cast(bf16x8, *(const u16x8v*)(sAabs + off));
            asg[mi] = __builtin_bit_cast(bf16x8, *(const u16x8v*)(sAsgn + off));
        }
#pragma unroll
        for (int ni = 0; ni < 4; ++ni) {
            int off = (wn + ni * 16 + l16) * LDK + quad * 8;
            bab[ni] = __builtin_bit_cast(bf16x8, *(const u16x8v*)(sBabs + off));
            bsg[ni] = __builtin_bit_cast(bf16x8, *(const u16x8v*)(sBsgn + off));
        }
#pragma unroll
        for (int mi = 0; mi < 4; ++mi)
#pragma unroll
            for (int ni = 0; ni < 4; ++ni) {
                accP[mi][ni] = __builtin_amdgcn_mfma_f32_16x16x32_bf16(
                    aab[mi], bab[ni], accP[mi][ni], 0, 0, 0);
                accS[mi][ni] = __builtin_amdgcn_mfma_f32_16x16x32_bf16(
                    asg[mi], bsg[ni], accS[mi][ni], 0, 0, 0);
            }
    }

    // Epilogue: C/D layout col = l16, row = quad*4 + reg
#pragma unroll
    for (int ni = 0; ni < 4; ++ni) {
        int n   = nb * BN + wn + ni * 16 + l16;
        float b = bias[n];
#pragma unroll
        for (int mi = 0; mi < 4; ++mi) {
            int mbase = mb * BM + wm + mi * 16 + quad * 4;
#pragma unroll
            for (int r = 0; r < 4; ++r) {
                float p = accP[mi][ni][r];
                float s = accS[mi][ni][r];
                float v = (s > 0.0f) ? p : ((s < 0.0f) ? -p : 0.0f);
                out[(size_t)(mbase + r) * N_DIM + n] = v + b;
            }
        }
    }
}

extern "C" void kernel_launch(void* const* d_in, const int* in_sizes, int n_in,
                              void* d_out, int out_size, void* d_ws, size_t ws_size,
                              hipStream_t stream) {
    const float* x    = (const float*)d_in[0];
    const float* w    = (const float*)d_in[1];
    const float* bias = (const float*)d_in[2];
    float* out        = (float*)d_out;

    const int M = in_sizes[0] / K_DIM;  // 262144

    dim3 grid(N_DIM / BN, M / BM, 1);   // (2, 2048): N fastest so paired blocks share x slab in L2/L3
    dim3 block(256, 1, 1);
    lns_gemm_kernel<<<grid, block, 0, stream>>>(x, w, bias, out, M);
}

// Round 2
// 494.257 us; speedup vs baseline: 1.0209x; 1.0209x over previous
//
#include <hip/hip_runtime.h>
#include <hip/hip_bf16.h>
#include <stdint.h>

// LNSLinear inference: out[m,n] = sign(S[m,n]) * P[m,n] + bias[n]
//   P = |x| @ |w|^T  (eps=1e-8 negligible at bf16), S = sign(x) @ sign(w)^T (exact)
// M = 262144, N = 256, K = 256.
// Structure: W pre-converted to bf16 abs|sgn in ws; main kernel streams x with
// global_load_lds (fp32, XOR-swizzled), double-buffered LDS, raw s_barrier +
// manual vmcnt so next tile's loads are in flight during compute.

#define K_DIM 256
#define N_DIM 256
#define BM 128
#define BN 128
#define BK 32
#define NKBLK 8  // K_DIM / BK

typedef float f32x4 __attribute__((ext_vector_type(4)));
typedef __bf16 bf16x8 __attribute__((ext_vector_type(8)));
typedef unsigned short u16x4v __attribute__((ext_vector_type(4)));
typedef unsigned short u16x8v __attribute__((ext_vector_type(8)));

// ---------- pre-kernel: W fp32 [N][K] -> ws bf16 rows [(n*8+kblk)][abs 32 | sgn 32] ----------
__global__ void w_convert_kernel(const float* __restrict__ W, unsigned short* __restrict__ Wp) {
    int t = blockIdx.x * 256 + threadIdx.x;  // 0..16383, each handles 4 k
    int n = t >> 6;
    int k = (t & 63) << 2;
    float4 v = *(const float4*)(W + (size_t)n * K_DIM + k);
    unsigned short* row = Wp + ((size_t)n * NKBLK + (k >> 5)) * 64;
    int pos = k & 31;
    float vv[4] = {v.x, v.y, v.z, v.w};
    u16x4v a, s;
#pragma unroll
    for (int j = 0; j < 4; ++j) {
        __bf16 h = (__bf16)__builtin_fabsf(vv[j]);
        a[j] = __builtin_bit_cast(unsigned short, h);
        unsigned int u = __float_as_uint(vv[j]);
        s[j] = (unsigned short)(0x3F80u | ((u >> 16) & 0x8000u));
    }
    *(u16x4v*)(row + pos) = a;
    *(u16x4v*)(row + 32 + pos) = s;
}

__device__ __forceinline__ void gload_lds16(const void* g, void* l) {
    __builtin_amdgcn_global_load_lds(
        (const __attribute__((address_space(1))) unsigned int*)g,
        (__attribute__((address_space(3))) unsigned int*)l, 16, 0, 0);
}

// ---------- main kernel ----------
__global__ __launch_bounds__(256, 2)
void lns_gemm_kernel(const float* __restrict__ X, const unsigned short* __restrict__ Wp,
                     const float* __restrict__ bias, float* __restrict__ out) {
    // A: [2 buf][128 rows][32 fp32] (row = 128 B = 8 chunks, XOR-swizzled)
    // B: [2 buf][128 rows][64 bf16] (row = abs32|sgn32 = 128 B = 8 chunks, XOR-swizzled)
    __shared__ __attribute__((aligned(16))) float sA[2][BM * BK];
    __shared__ __attribute__((aligned(16))) unsigned short sB[2][BN * 64];

    const int tid  = threadIdx.x;
    const int lane = tid & 63;
    const int wave = tid >> 6;
    const int quad = lane >> 4;
    const int l16  = lane & 15;
    const int mb   = blockIdx.y;
    const int nb   = blockIdx.x;
    const int wm   = (wave >> 1) * 64;
    const int wn   = (wave & 1) * 64;

    const float* Ax = X + (size_t)(mb * BM) * K_DIM;
    const unsigned short* Bw = Wp + (size_t)(nb * BN) * (NKBLK * 64);

    // Per-thread staging source pointers (advance 128 B per k-iter).
    // chunk id f = i*256 + tid; row r = f>>3; slot c = f&7 holds global chunk g = c ^ (r&7).
    const float* gA[4];
    const unsigned short* gB[4];
#pragma unroll
    for (int i = 0; i < 4; ++i) {
        int f = i * 256 + tid;
        int r = f >> 3;
        int g = (f & 7) ^ (r & 7);
        gA[i] = Ax + (size_t)r * K_DIM + g * 4;
        gB[i] = Bw + ((size_t)r * NKBLK) * 64 + g * 8;
    }

    f32x4 accP[4][4];
    f32x4 accS[4][4];
#pragma unroll
    for (int i = 0; i < 4; ++i)
#pragma unroll
        for (int j = 0; j < 4; ++j) {
            accP[i][j] = (f32x4)(0.0f);
            accS[i][j] = (f32x4)(0.0f);
        }

    // Prologue: issue iter-0 tiles into buf 0.
#pragma unroll
    for (int i = 0; i < 4; ++i) {
        gload_lds16(gA[i], &sA[0][(i * 256 + wave * 64) * 4]);
        gA[i] += BK;
    }
#pragma unroll
    for (int i = 0; i < 4; ++i) {
        gload_lds16(gB[i], &sB[0][(i * 256 + wave * 64) * 8]);
        gB[i] += 64;
    }

    for (int kb = 0; kb < NKBLK; ++kb) {
        const int cur = kb & 1;
        if (kb + 1 < NKBLK) {
            const int nxt = cur ^ 1;
#pragma unroll
            for (int i = 0; i < 4; ++i) {
                gload_lds16(gA[i], &sA[nxt][(i * 256 + wave * 64) * 4]);
                gA[i] += BK;
            }
#pragma unroll
            for (int i = 0; i < 4; ++i) {
                gload_lds16(gB[i], &sB[nxt][(i * 256 + wave * 64) * 8]);
                gB[i] += 64;
            }
            // Wait only for current iter's 8 loads (the 8 just-issued may remain in flight).
            asm volatile("s_waitcnt vmcnt(8)\n\ts_barrier" ::: "memory");
        } else {
            asm volatile("s_waitcnt vmcnt(0)\n\ts_barrier" ::: "memory");
        }

        // ---- fragments ----
        bf16x8 aab[4], asg[4], bab[4], bsg[4];
#pragma unroll
        for (int mi = 0; mi < 4; ++mi) {
            int m = wm + mi * 16 + l16;
            const float* rowp = &sA[cur][m * BK];
            int s0 = (2 * quad) ^ (m & 7);
            f32x4 f0 = *(const f32x4*)(rowp + s0 * 4);
            f32x4 f1 = *(const f32x4*)(rowp + (s0 ^ 1) * 4);
            u16x8v ab, sg;
#pragma unroll
            for (int j = 0; j < 4; ++j) {
                __bf16 h0 = (__bf16)__builtin_fabsf(f0[j]);
                __bf16 h1 = (__bf16)__builtin_fabsf(f1[j]);
                ab[j]     = __builtin_bit_cast(unsigned short, h0);
                ab[j + 4] = __builtin_bit_cast(unsigned short, h1);
                unsigned int u0 = __float_as_uint(f0[j]);
                unsigned int u1 = __float_as_uint(f1[j]);
                sg[j]     = (unsigned short)(0x3F80u | ((u0 >> 16) & 0x8000u));
                sg[j + 4] = (unsigned short)(0x3F80u | ((u1 >> 16) & 0x8000u));
            }
            aab[mi] = __builtin_bit_cast(bf16x8, ab);
            asg[mi] = __builtin_bit_cast(bf16x8, sg);
        }
#pragma unroll
        for (int ni = 0; ni < 4; ++ni) {
            int r = wn + ni * 16 + l16;
            const unsigned short* rp = &sB[cur][r * 64];
            int sa = quad ^ (r & 7);
            bab[ni] = __builtin_bit_cast(bf16x8, *(const u16x8v*)(rp + sa * 8));
            bsg[ni] = __builtin_bit_cast(bf16x8, *(const u16x8v*)(rp + (sa ^ 4) * 8));
        }
#pragma unroll
        for (int mi = 0; mi < 4; ++mi)
#pragma unroll
            for (int ni = 0; ni < 4; ++ni) {
                accP[mi][ni] = __builtin_amdgcn_mfma_f32_16x16x32_bf16(
                    aab[mi], bab[ni], accP[mi][ni], 0, 0, 0);
                accS[mi][ni] = __builtin_amdgcn_mfma_f32_16x16x32_bf16(
                    asg[mi], bsg[ni], accS[mi][ni], 0, 0, 0);
            }

        // All waves done reading this buffer before anyone's next issue overwrites it.
        asm volatile("s_waitcnt lgkmcnt(0)\n\ts_barrier" ::: "memory");
    }

    // ---- epilogue: C/D layout col = l16, row = quad*4 + reg ----
#pragma unroll
    for (int ni = 0; ni < 4; ++ni) {
        int n   = nb * BN + wn + ni * 16 + l16;
        float b = bias[n];
#pragma unroll
        for (int mi = 0; mi < 4; ++mi) {
            int mbase = mb * BM + wm + mi * 16 + quad * 4;
#pragma unroll
            for (int r = 0; r < 4; ++r) {
                float p = accP[mi][ni][r];
                float s = accS[mi][ni][r];
                float v = (s > 0.0f) ? p : ((s < 0.0f) ? -p : 0.0f);
                out[(size_t)(mbase + r) * N_DIM + n] = v + b;
            }
        }
    }
}

extern "C" void kernel_launch(void* const* d_in, const int* in_sizes, int n_in,
                              void* d_out, int out_size, void* d_ws, size_t ws_size,
                              hipStream_t stream) {
    const float* x    = (const float*)d_in[0];
    const float* w    = (const float*)d_in[1];
    const float* bias = (const float*)d_in[2];
    float* out        = (float*)d_out;
    unsigned short* Wp = (unsigned short*)d_ws;  // 256 KB: [n][kblk][abs32|sgn32] bf16

    const int M = in_sizes[0] / K_DIM;  // 262144

    w_convert_kernel<<<dim3(64, 1, 1), dim3(256, 1, 1), 0, stream>>>(w, Wp);

    dim3 grid(N_DIM / BN, M / BM, 1);  // (2, 2048): nb fastest -> paired blocks share x slab in L2/L3
    dim3 block(256, 1, 1);
    lns_gemm_kernel<<<grid, block, 0, stream>>>(x, Wp, bias, out);
}